// Round 9
// baseline (630.546 us; speedup 1.0000x reference)
//
#include <hip/hip_runtime.h>
#include <hip/hip_bf16.h>

// ColorINN R9: 3-blocks/CU round. A2 LDS 32KB (no bias frags); b2/b3 enter as
// f32 C-initializers of the MFMA (VMEM pipe is idle); aug trick removed
// (-9 MFMA/s-iter). 256-thread blocks, wave = 128 pts, h staged packed-bf16.

#define MEMBAR() asm volatile("" ::: "memory")

typedef float f32x4 __attribute__((ext_vector_type(4)));
typedef short s16x8 __attribute__((ext_vector_type(8)));
typedef short s16x4 __attribute__((ext_vector_type(4)));
typedef int   i32x4 __attribute__((ext_vector_type(4)));

#define MFMA(a,b,c) __builtin_amdgcn_mfma_f32_16x16x32_bf16((a),(b),(c),0,0,0)

__device__ __forceinline__ unsigned cvtpk(float a, float b){
  unsigned r;
  asm("v_cvt_pk_bf16_f32 %0, %1, %2" : "=v"(r) : "v"(a), "v"(b));
  return r;   // lo = bf16(a), hi = bf16(b)
}
__device__ __forceinline__ unsigned short f2bf(float f){
  unsigned u = __float_as_uint(f);
  return (unsigned short)((u + 0x7FFFu + ((u >> 16) & 1u)) >> 16);
}

// tanh-form GELU: x*(1 - 1/(1+exp2(x*(2.3022077 + 0.1029432 x^2))))
__device__ __forceinline__ float gelu_f(float x){
  float x2 = x*x;
  float w = x * __builtin_fmaf(0.1029432f, x2, 2.3022077f);
  float e = __builtin_amdgcn_exp2f(w);
  float r = __builtin_amdgcn_rcpf(1.0f + e);
  return __builtin_fmaf(-x, r, x);
}

__global__ __launch_bounds__(256, 3) void inn_main(
    const float* __restrict__ XYZ,
    const float* __restrict__ W1, const float* __restrict__ b1,
    const float* __restrict__ W2, const float* __restrict__ b2,
    const float* __restrict__ W3, const float* __restrict__ b3,
    const float* __restrict__ gg, const float* __restrict__ off,
    const float* __restrict__ Pm,
    float* __restrict__ outp)
{
  // A2: 32 frags (mf*4+kc) x 1KB.  h: 4 waves x 4352B.  Total 49.4 KB -> 3 blocks/CU.
  __shared__ __align__(16) unsigned char ldsA2[32*1024];
  __shared__ __align__(16) unsigned char ldsH[4*4352];

  const int tid  = threadIdx.x;
  const int wid  = tid >> 6;
  const int lane = tid & 63;
  const int p    = lane & 15;
  const int g    = lane >> 4;
  unsigned char* hb = ldsH + wid*4352;
  const long base_pt = (long)blockIdx.x*512 + wid*128;
  const f32x4 z4 = {0.f,0.f,0.f,0.f};

  // per-point state in registers (statically indexed)
  f32x4 xst[8];
  #pragma unroll
  for (int s = 0; s < 8; ++s) {
    long pt = base_pt + s*16 + p;
    xst[s][0] = XYZ[pt*3+0];
    xst[s][1] = XYZ[pt*3+1];
    xst[s][2] = XYZ[pt*3+2];
    xst[s][3] = 0.f;
  }

  for (int l = 0; l < 8; ++l) {
    __syncthreads();   // prev layer's A2 reads complete before overwrite

    // ---- cooperative A2 staging: wave wid stages frags wid*8 .. wid*8+7 ----
    #pragma unroll
    for (int q = 0; q < 8; ++q) {
      int f  = wid*8 + q;
      int mf = f >> 2, kc = f & 3;
      const float* rw = W2 + l*16384 + (16*mf + p)*128 + 32*kc + 8*g;
      f32x4 u0 = *(const f32x4*)rw;
      f32x4 u1 = *(const f32x4*)(rw + 4);
      i32x4 w;
      w[0] = (int)cvtpk(u0[0], u0[1]); w[1] = (int)cvtpk(u0[2], u0[3]);
      w[2] = (int)cvtpk(u1[0], u1[1]); w[3] = (int)cvtpk(u1[2], u1[3]);
      *(i32x4*)(ldsA2 + f*1024 + lane*16) = w;
    }

    // ---- per-wave register fragments: A1 (W1+b1 aug), A3 (0.1*W3) ----
    s16x8 A1[8];
    #pragma unroll
    for (int mf = 0; mf < 8; ++mf) {
      s16x8 t = (s16x8){0,0,0,0,0,0,0,0};
      if (g == 0) {
        int row = 16*mf + p;
        t[0] = (short)f2bf(W1[l*256 + row*2 + 0]);
        t[1] = (short)f2bf(W1[l*256 + row*2 + 1]);
        t[2] = (short)f2bf(b1[l*128 + row]);
      }
      A1[mf] = t;
    }
    s16x8 A3[4];
    #pragma unroll
    for (int kc = 0; kc < 4; ++kc) {
      s16x8 t = (s16x8){0,0,0,0,0,0,0,0};
      if (p < 4) {
        const float* rw = W3 + l*512 + p*128 + 8*g + 32*kc;
        f32x4 u0 = *(const f32x4*)(rw);
        f32x4 u1 = *(const f32x4*)(rw + 4);
        i32x4 w;
        w[0] = (int)cvtpk(0.1f*u0[0], 0.1f*u0[1]); w[1] = (int)cvtpk(0.1f*u0[2], 0.1f*u0[3]);
        w[2] = (int)cvtpk(0.1f*u1[0], 0.1f*u1[1]); w[3] = (int)cvtpk(0.1f*u1[2], 0.1f*u1[3]);
        __builtin_memcpy(&t, &w, 16);
      }
      A3[kc] = t;
    }
    // bias C-initializers (f32): b2 rows 16mf+4g.., b3 rows 0..3 on g==0
    f32x4 b2v[8];
    #pragma unroll
    for (int mf = 0; mf < 8; ++mf)
      b2v[mf] = *(const f32x4*)(b2 + l*128 + 16*mf + 4*g);
    f32x4 b3v = z4;
    if (g == 0) {
      f32x4 t = *(const f32x4*)(b3 + l*4);
      #pragma unroll
      for (int i = 0; i < 4; ++i) b3v[i] = 0.1f*t[i];
    }
    float scl[4];
    #pragma unroll
    for (int j = 0; j < 4; ++j)
      scl[j] = 0.2f * log1pf(expf(0.5f * gg[l*4 + j]));
    float PS[16], PB[4];
    #pragma unroll
    for (int i = 0; i < 4; ++i) {
      float acc = 0.f;
      #pragma unroll
      for (int j = 0; j < 4; ++j) {
        float pv = Pm[l*16 + 4*i + j];
        PS[4*i+j] = pv*scl[j];
        acc = __builtin_fmaf(pv, off[l*4+j], acc);
      }
      PB[i] = acc;
    }

    __syncthreads();   // A2 staged before any wave reads it

    #pragma unroll
    for (int s = 0; s < 8; ++s) {
      // ---- G1: h1 = gelu(W1aug @ [x0;x1;1]) ----
      s16x8 bx = (s16x8){0,0,0,0,0,0,0,0};
      if (g == 0) {
        unsigned b01 = cvtpk(xst[s][0], xst[s][1]);
        bx[0] = (short)(b01 & 0xFFFFu);
        bx[1] = (short)(b01 >> 16);
        bx[2] = (short)0x3F80;
      }
      f32x4 c1[8];
      #pragma unroll
      for (int mf = 0; mf < 8; ++mf) c1[mf] = MFMA(A1[mf], bx, z4);

      MEMBAR();
      #pragma unroll
      for (int m = 0; m < 4; ++m) {     // packed-bf16 h write (R2-verified layout)
        i32x4 w;
        w[0] = (int)cvtpk(gelu_f(c1[2*m][0]),   gelu_f(c1[2*m][1]));
        w[1] = (int)cvtpk(gelu_f(c1[2*m][2]),   gelu_f(c1[2*m][3]));
        w[2] = (int)cvtpk(gelu_f(c1[2*m+1][0]), gelu_f(c1[2*m+1][1]));
        w[3] = (int)cvtpk(gelu_f(c1[2*m+1][2]), gelu_f(c1[2*m+1][3]));
        *(i32x4*)(hb + p*272 + (4*m + g)*16) = w;
      }
      MEMBAR();

      // ---- G2: h2 = gelu(W2 @ h1 + b2) ----
      f32x4 c2[8];
      #pragma unroll
      for (int mf = 0; mf < 8; ++mf) c2[mf] = b2v[mf];   // bias as C-init
      #pragma unroll
      for (int kc = 0; kc < 4; ++kc) {
        const unsigned char* ra = hb + p*272 + (4*kc + 2*(g & 1))*16 + (g >> 1)*8;
        s16x4 lo = *(const s16x4*)(ra);
        s16x4 hi = *(const s16x4*)(ra + 16);
        s16x8 bfr = __builtin_shufflevector(lo, hi, 0,1,2,3,4,5,6,7);
        #pragma unroll
        for (int mf = 0; mf < 8; ++mf) {
          s16x8 af = *(const s16x8*)(ldsA2 + (mf*4 + kc)*1024 + lane*16);
          c2[mf] = MFMA(af, bfr, c2[mf]);
        }
      }

      MEMBAR();
      #pragma unroll
      for (int m = 0; m < 4; ++m) {     // h2 overwrites h1 (sequential use)
        i32x4 w;
        w[0] = (int)cvtpk(gelu_f(c2[2*m][0]),   gelu_f(c2[2*m][1]));
        w[1] = (int)cvtpk(gelu_f(c2[2*m][2]),   gelu_f(c2[2*m][3]));
        w[2] = (int)cvtpk(gelu_f(c2[2*m+1][0]), gelu_f(c2[2*m+1][1]));
        w[3] = (int)cvtpk(gelu_f(c2[2*m+1][2]), gelu_f(c2[2*m+1][3]));
        *(i32x4*)(hb + p*272 + (4*m + g)*16) = w;
      }
      MEMBAR();

      // ---- G3: a = 0.1*(W3 @ h2) + 0.1*b3 (bias as C-init) ----
      f32x4 c3 = b3v;
      #pragma unroll
      for (int kc = 0; kc < 4; ++kc) {
        const unsigned char* ra = hb + p*272 + (4*kc + 2*(g & 1))*16 + (g >> 1)*8;
        s16x4 lo = *(const s16x4*)(ra);
        s16x4 hi = *(const s16x4*)(ra + 16);
        s16x8 bfr = __builtin_shufflevector(lo, hi, 0,1,2,3,4,5,6,7);
        c3 = MFMA(A3[kc], bfr, c3);
      }

      // broadcast a[0..3] (rows 0..3 live on lanes 0..15) to all lanes
      int addr = p << 2;
      float a0 = __int_as_float(__builtin_amdgcn_ds_bpermute(addr, __float_as_int(c3[0])));
      float a1 = __int_as_float(__builtin_amdgcn_ds_bpermute(addr, __float_as_int(c3[1])));
      float a2 = __int_as_float(__builtin_amdgcn_ds_bpermute(addr, __float_as_int(c3[2])));
      float a3 = __int_as_float(__builtin_amdgcn_ds_bpermute(addr, __float_as_int(c3[3])));

      // tail: s=2tanh(a) => exp(s) = exp2(2.8853901 - 5.7707802/(1+exp2(2.8853901*a)))
      float t0 = __builtin_amdgcn_rcpf(1.f + __builtin_amdgcn_exp2f(2.8853901f * a0));
      float t1 = __builtin_amdgcn_rcpf(1.f + __builtin_amdgcn_exp2f(2.8853901f * a1));
      float e0 = __builtin_amdgcn_exp2f(__builtin_fmaf(-5.7707802f, t0, 2.8853901f));
      float e1 = __builtin_amdgcn_exp2f(__builtin_fmaf(-5.7707802f, t1, 2.8853901f));
      float v2 = __builtin_fmaf(xst[s][2], e0, a2);
      float v3 = __builtin_fmaf(xst[s][3], e1, a3);
      f32x4 y;
      #pragma unroll
      for (int i = 0; i < 4; ++i)
        y[i] = __builtin_fmaf(PS[4*i+0], xst[s][0], __builtin_fmaf(PS[4*i+1], xst[s][1],
               __builtin_fmaf(PS[4*i+2], v2, __builtin_fmaf(PS[4*i+3], v3, PB[i]))));
      xst[s] = y;   // replicated across all lanes
    }
  }

  if (g == 0) {
    #pragma unroll
    for (int s = 0; s < 8; ++s) {
      long pt = base_pt + s*16 + p;
      outp[pt*3+0] = xst[s][0];
      outp[pt*3+1] = xst[s][1];
      outp[pt*3+2] = xst[s][2];
    }
  }
}

extern "C" void kernel_launch(void* const* d_in, const int* in_sizes, int n_in,
                              void* d_out, int out_size, void* d_ws, size_t ws_size,
                              hipStream_t stream)
{
  const float* XYZ = (const float*)d_in[0];
  const float* W1  = (const float*)d_in[1];
  const float* b1  = (const float*)d_in[2];
  const float* W2  = (const float*)d_in[3];
  const float* b2  = (const float*)d_in[4];
  const float* W3  = (const float*)d_in[5];
  const float* b3  = (const float*)d_in[6];
  const float* g   = (const float*)d_in[7];
  const float* off = (const float*)d_in[8];
  const float* P   = (const float*)d_in[9];

  int Bn = in_sizes[0] / 3;          // 524288
  int nblocks = Bn / 512;            // 1024 exact
  inn_main<<<nblocks, 256, 0, stream>>>(XYZ, W1, b1, W2, b2, W3, b3, g, off, P,
                                        (float*)d_out);
}

// Round 10
// 487.595 us; speedup vs baseline: 1.2932x; 1.2932x over previous
//
#include <hip/hip_runtime.h>
#include <hip/hip_bf16.h>

// ColorINN R10: 3-blocks/CU via LDS shrink ONLY; register budget left relaxed
// (R9's launch_bounds(256,3) caused catastrophic scratch spill: VGPR 84,
// 1.2GB/dispatch scratch traffic). b2 staged in LDS f32 (broadcast reads);
// b3 as C-init; A2 32KB in LDS; h packed-bf16 per wave; state in registers.

#define MEMBAR() asm volatile("" ::: "memory")

typedef float f32x4 __attribute__((ext_vector_type(4)));
typedef short s16x8 __attribute__((ext_vector_type(8)));
typedef short s16x4 __attribute__((ext_vector_type(4)));
typedef int   i32x4 __attribute__((ext_vector_type(4)));

#define MFMA(a,b,c) __builtin_amdgcn_mfma_f32_16x16x32_bf16((a),(b),(c),0,0,0)

__device__ __forceinline__ unsigned cvtpk(float a, float b){
  unsigned r;
  asm("v_cvt_pk_bf16_f32 %0, %1, %2" : "=v"(r) : "v"(a), "v"(b));
  return r;   // lo = bf16(a), hi = bf16(b)
}
__device__ __forceinline__ unsigned short f2bf(float f){
  unsigned u = __float_as_uint(f);
  return (unsigned short)((u + 0x7FFFu + ((u >> 16) & 1u)) >> 16);
}

// tanh-form GELU: x*(1 - 1/(1+exp2(x*(2.3022077 + 0.1029432 x^2))))
__device__ __forceinline__ float gelu_f(float x){
  float x2 = x*x;
  float w = x * __builtin_fmaf(0.1029432f, x2, 2.3022077f);
  float e = __builtin_amdgcn_exp2f(w);
  float r = __builtin_amdgcn_rcpf(1.0f + e);
  return __builtin_fmaf(-x, r, x);
}

__global__ __launch_bounds__(256, 2) void inn_main(
    const float* __restrict__ XYZ,
    const float* __restrict__ W1, const float* __restrict__ b1,
    const float* __restrict__ W2, const float* __restrict__ b2,
    const float* __restrict__ W3, const float* __restrict__ b3,
    const float* __restrict__ gg, const float* __restrict__ off,
    const float* __restrict__ Pm,
    float* __restrict__ outp)
{
  // A2: 32 frags x 1KB + b2 f32 (512B) + h: 4 waves x 4352B  = 49.9 KB -> 3 blocks/CU.
  __shared__ __align__(16) unsigned char ldsA2[32*1024];
  __shared__ __align__(16) float ldsB2[128];
  __shared__ __align__(16) unsigned char ldsH[4*4352];

  const int tid  = threadIdx.x;
  const int wid  = tid >> 6;
  const int lane = tid & 63;
  const int p    = lane & 15;
  const int g    = lane >> 4;
  unsigned char* hb = ldsH + wid*4352;
  const long base_pt = (long)blockIdx.x*512 + wid*128;
  const f32x4 z4 = {0.f,0.f,0.f,0.f};

  // per-point state in registers (statically indexed)
  f32x4 xst[8];
  #pragma unroll
  for (int s = 0; s < 8; ++s) {
    long pt = base_pt + s*16 + p;
    xst[s][0] = XYZ[pt*3+0];
    xst[s][1] = XYZ[pt*3+1];
    xst[s][2] = XYZ[pt*3+2];
    xst[s][3] = 0.f;
  }

  for (int l = 0; l < 8; ++l) {
    __syncthreads();   // prev layer's A2/b2 reads complete before overwrite

    // ---- cooperative staging: wave wid stages A2 frags wid*8..wid*8+7; b2 by tid<128 ----
    #pragma unroll
    for (int q = 0; q < 8; ++q) {
      int f  = wid*8 + q;
      int mf = f >> 2, kc = f & 3;
      const float* rw = W2 + l*16384 + (16*mf + p)*128 + 32*kc + 8*g;
      f32x4 u0 = *(const f32x4*)rw;
      f32x4 u1 = *(const f32x4*)(rw + 4);
      i32x4 w;
      w[0] = (int)cvtpk(u0[0], u0[1]); w[1] = (int)cvtpk(u0[2], u0[3]);
      w[2] = (int)cvtpk(u1[0], u1[1]); w[3] = (int)cvtpk(u1[2], u1[3]);
      *(i32x4*)(ldsA2 + f*1024 + lane*16) = w;
    }
    if (tid < 128) ldsB2[tid] = b2[l*128 + tid];

    // ---- per-wave register fragments: A1 (W1+b1 aug), A3 (0.1*W3) ----
    s16x8 A1[8];
    #pragma unroll
    for (int mf = 0; mf < 8; ++mf) {
      s16x8 t = (s16x8){0,0,0,0,0,0,0,0};
      if (g == 0) {
        int row = 16*mf + p;
        t[0] = (short)f2bf(W1[l*256 + row*2 + 0]);
        t[1] = (short)f2bf(W1[l*256 + row*2 + 1]);
        t[2] = (short)f2bf(b1[l*128 + row]);
      }
      A1[mf] = t;
    }
    s16x8 A3[4];
    #pragma unroll
    for (int kc = 0; kc < 4; ++kc) {
      s16x8 t = (s16x8){0,0,0,0,0,0,0,0};
      if (p < 4) {
        const float* rw = W3 + l*512 + p*128 + 8*g + 32*kc;
        f32x4 u0 = *(const f32x4*)(rw);
        f32x4 u1 = *(const f32x4*)(rw + 4);
        i32x4 w;
        w[0] = (int)cvtpk(0.1f*u0[0], 0.1f*u0[1]); w[1] = (int)cvtpk(0.1f*u0[2], 0.1f*u0[3]);
        w[2] = (int)cvtpk(0.1f*u1[0], 0.1f*u1[1]); w[3] = (int)cvtpk(0.1f*u1[2], 0.1f*u1[3]);
        __builtin_memcpy(&t, &w, 16);
      }
      A3[kc] = t;
    }
    f32x4 b3v = z4;
    if (g == 0) {
      f32x4 t = *(const f32x4*)(b3 + l*4);
      #pragma unroll
      for (int i = 0; i < 4; ++i) b3v[i] = 0.1f*t[i];
    }
    float scl[4];
    #pragma unroll
    for (int j = 0; j < 4; ++j)
      scl[j] = 0.2f * log1pf(expf(0.5f * gg[l*4 + j]));
    float PS[16], PB[4];
    #pragma unroll
    for (int i = 0; i < 4; ++i) {
      float acc = 0.f;
      #pragma unroll
      for (int j = 0; j < 4; ++j) {
        float pv = Pm[l*16 + 4*i + j];
        PS[4*i+j] = pv*scl[j];
        acc = __builtin_fmaf(pv, off[l*4+j], acc);
      }
      PB[i] = acc;
    }

    __syncthreads();   // A2/b2 staged before any wave reads

    #pragma unroll
    for (int s = 0; s < 8; ++s) {
      // ---- G1: h1 = gelu(W1aug @ [x0;x1;1]) ----
      s16x8 bx = (s16x8){0,0,0,0,0,0,0,0};
      if (g == 0) {
        unsigned b01 = cvtpk(xst[s][0], xst[s][1]);
        bx[0] = (short)(b01 & 0xFFFFu);
        bx[1] = (short)(b01 >> 16);
        bx[2] = (short)0x3F80;
      }
      f32x4 c1[8];
      #pragma unroll
      for (int mf = 0; mf < 8; ++mf) c1[mf] = MFMA(A1[mf], bx, z4);

      MEMBAR();
      #pragma unroll
      for (int m = 0; m < 4; ++m) {     // packed-bf16 h write (R2-verified layout)
        i32x4 w;
        w[0] = (int)cvtpk(gelu_f(c1[2*m][0]),   gelu_f(c1[2*m][1]));
        w[1] = (int)cvtpk(gelu_f(c1[2*m][2]),   gelu_f(c1[2*m][3]));
        w[2] = (int)cvtpk(gelu_f(c1[2*m+1][0]), gelu_f(c1[2*m+1][1]));
        w[3] = (int)cvtpk(gelu_f(c1[2*m+1][2]), gelu_f(c1[2*m+1][3]));
        *(i32x4*)(hb + p*272 + (4*m + g)*16) = w;
      }
      MEMBAR();

      // ---- G2: h2 = gelu(W2 @ h1 + b2); bias C-init from LDS broadcast ----
      f32x4 c2[8];
      #pragma unroll
      for (int mf = 0; mf < 8; ++mf)
        c2[mf] = *(const f32x4*)&ldsB2[16*mf + 4*g];
      #pragma unroll
      for (int kc = 0; kc < 4; ++kc) {
        const unsigned char* ra = hb + p*272 + (4*kc + 2*(g & 1))*16 + (g >> 1)*8;
        s16x4 lo = *(const s16x4*)(ra);
        s16x4 hi = *(const s16x4*)(ra + 16);
        s16x8 bfr = __builtin_shufflevector(lo, hi, 0,1,2,3,4,5,6,7);
        #pragma unroll
        for (int mf = 0; mf < 8; ++mf) {
          s16x8 af = *(const s16x8*)(ldsA2 + (mf*4 + kc)*1024 + lane*16);
          c2[mf] = MFMA(af, bfr, c2[mf]);
        }
      }

      MEMBAR();
      #pragma unroll
      for (int m = 0; m < 4; ++m) {     // h2 overwrites h1 (sequential use)
        i32x4 w;
        w[0] = (int)cvtpk(gelu_f(c2[2*m][0]),   gelu_f(c2[2*m][1]));
        w[1] = (int)cvtpk(gelu_f(c2[2*m][2]),   gelu_f(c2[2*m][3]));
        w[2] = (int)cvtpk(gelu_f(c2[2*m+1][0]), gelu_f(c2[2*m+1][1]));
        w[3] = (int)cvtpk(gelu_f(c2[2*m+1][2]), gelu_f(c2[2*m+1][3]));
        *(i32x4*)(hb + p*272 + (4*m + g)*16) = w;
      }
      MEMBAR();

      // ---- G3: a = 0.1*(W3 @ h2) + 0.1*b3 (bias as C-init) ----
      f32x4 c3 = b3v;
      #pragma unroll
      for (int kc = 0; kc < 4; ++kc) {
        const unsigned char* ra = hb + p*272 + (4*kc + 2*(g & 1))*16 + (g >> 1)*8;
        s16x4 lo = *(const s16x4*)(ra);
        s16x4 hi = *(const s16x4*)(ra + 16);
        s16x8 bfr = __builtin_shufflevector(lo, hi, 0,1,2,3,4,5,6,7);
        c3 = MFMA(A3[kc], bfr, c3);
      }

      // broadcast a[0..3] (rows 0..3 live on lanes 0..15) to all lanes
      int addr = p << 2;
      float a0 = __int_as_float(__builtin_amdgcn_ds_bpermute(addr, __float_as_int(c3[0])));
      float a1 = __int_as_float(__builtin_amdgcn_ds_bpermute(addr, __float_as_int(c3[1])));
      float a2 = __int_as_float(__builtin_amdgcn_ds_bpermute(addr, __float_as_int(c3[2])));
      float a3 = __int_as_float(__builtin_amdgcn_ds_bpermute(addr, __float_as_int(c3[3])));

      // tail: s=2tanh(a) => exp(s) = exp2(2.8853901 - 5.7707802/(1+exp2(2.8853901*a)))
      float t0 = __builtin_amdgcn_rcpf(1.f + __builtin_amdgcn_exp2f(2.8853901f * a0));
      float t1 = __builtin_amdgcn_rcpf(1.f + __builtin_amdgcn_exp2f(2.8853901f * a1));
      float e0 = __builtin_amdgcn_exp2f(__builtin_fmaf(-5.7707802f, t0, 2.8853901f));
      float e1 = __builtin_amdgcn_exp2f(__builtin_fmaf(-5.7707802f, t1, 2.8853901f));
      float v2 = __builtin_fmaf(xst[s][2], e0, a2);
      float v3 = __builtin_fmaf(xst[s][3], e1, a3);
      f32x4 y;
      #pragma unroll
      for (int i = 0; i < 4; ++i)
        y[i] = __builtin_fmaf(PS[4*i+0], xst[s][0], __builtin_fmaf(PS[4*i+1], xst[s][1],
               __builtin_fmaf(PS[4*i+2], v2, __builtin_fmaf(PS[4*i+3], v3, PB[i]))));
      xst[s] = y;   // replicated across all lanes
    }
  }

  if (g == 0) {
    #pragma unroll
    for (int s = 0; s < 8; ++s) {
      long pt = base_pt + s*16 + p;
      outp[pt*3+0] = xst[s][0];
      outp[pt*3+1] = xst[s][1];
      outp[pt*3+2] = xst[s][2];
    }
  }
}

extern "C" void kernel_launch(void* const* d_in, const int* in_sizes, int n_in,
                              void* d_out, int out_size, void* d_ws, size_t ws_size,
                              hipStream_t stream)
{
  const float* XYZ = (const float*)d_in[0];
  const float* W1  = (const float*)d_in[1];
  const float* b1  = (const float*)d_in[2];
  const float* W2  = (const float*)d_in[3];
  const float* b2  = (const float*)d_in[4];
  const float* W3  = (const float*)d_in[5];
  const float* b3  = (const float*)d_in[6];
  const float* g   = (const float*)d_in[7];
  const float* off = (const float*)d_in[8];
  const float* P   = (const float*)d_in[9];

  int Bn = in_sizes[0] / 3;          // 524288
  int nblocks = Bn / 512;            // 1024 exact
  inn_main<<<nblocks, 256, 0, stream>>>(XYZ, W1, b1, W2, b2, W3, b3, g, off, P,
                                        (float*)d_out);
}

// Round 12
// 454.571 us; speedup vs baseline: 1.3871x; 1.0726x over previous
//
#include <hip/hip_runtime.h>
#include <hip/hip_bf16.h>

// ColorINN R12: R11 with the cvt_pkrtz vector-type mismatch fixed (bit-cast
// via memcpy; __fp16x2 and _Float16x2 are layout-identical). GELU = trans-free
// packed-f16 deg-9 odd poly; datapath = mfma_f32_16x16x32_f16. Structure=R10.

#define MEMBAR() asm volatile("" ::: "memory")

typedef float    f32x4 __attribute__((ext_vector_type(4)));
typedef short    s16x4 __attribute__((ext_vector_type(4)));
typedef int      i32x4 __attribute__((ext_vector_type(4)));
typedef _Float16 h16x2 __attribute__((ext_vector_type(2)));
typedef _Float16 h16x8 __attribute__((ext_vector_type(8)));

#define MFMA(a,b,c) __builtin_amdgcn_mfma_f32_16x16x32_f16((a),(b),(c),0,0,0)

// f32 pair -> packed f16 via v_cvt_pkrtz_f16_f32 (bit-cast around __fp16x2)
__device__ __forceinline__ h16x2 pkrtz(float a, float b){
  auto t = __builtin_amdgcn_cvt_pkrtz(a, b);
  h16x2 r; __builtin_memcpy(&r, &t, 4); return r;
}
__device__ __forceinline__ unsigned pkh(float a, float b){
  auto t = __builtin_amdgcn_cvt_pkrtz(a, b);
  unsigned r; __builtin_memcpy(&r, &t, 4); return r;
}

// packed GELU: y = x * (0.5 + xc*D(xc^2)), xc = clamp(x,±3.75)/4,
// deg-4 poly in xc^2 (odd deg-9 overall), exact at clamp. No transcendentals.
__device__ __forceinline__ h16x2 gelu_pk(h16x2 x){
  const h16x2 Q   = {(_Float16)0.25f,      (_Float16)0.25f};
  const h16x2 CLO = {(_Float16)-0.9375f,   (_Float16)-0.9375f};
  const h16x2 CHI = {(_Float16)0.9375f,    (_Float16)0.9375f};
  const h16x2 D4  = {(_Float16)2.639031f,  (_Float16)2.639031f};
  const h16x2 D3  = {(_Float16)-6.920503f, (_Float16)-6.920503f};
  const h16x2 D2  = {(_Float16)7.180759f,  (_Float16)7.180759f};
  const h16x2 D1  = {(_Float16)-3.960064f, (_Float16)-3.960064f};
  const h16x2 D0  = {(_Float16)1.590628f,  (_Float16)1.590628f};
  const h16x2 H   = {(_Float16)0.5f,       (_Float16)0.5f};
  h16x2 xs = x * Q;
  xs = __builtin_elementwise_max(xs, CLO);
  xs = __builtin_elementwise_min(xs, CHI);
  h16x2 t = xs * xs;
  h16x2 s = t*D4 + D3;
  s = s*t + D2;
  s = s*t + D1;
  s = s*t + D0;
  h16x2 phi = xs*s + H;
  return x * phi;
}

// 4 f32 (one C-frag reg group) -> 2 packed-f16 gelu results (raw u32 pair)
__device__ __forceinline__ void gelu4(const f32x4 c, unsigned& w0, unsigned& w1){
  h16x2 p0 = gelu_pk(pkrtz(c[0], c[1]));
  h16x2 p1 = gelu_pk(pkrtz(c[2], c[3]));
  __builtin_memcpy(&w0, &p0, 4);
  __builtin_memcpy(&w1, &p1, 4);
}

__global__ __launch_bounds__(256, 2) void inn_main(
    const float* __restrict__ XYZ,
    const float* __restrict__ W1, const float* __restrict__ b1,
    const float* __restrict__ W2, const float* __restrict__ b2,
    const float* __restrict__ W3, const float* __restrict__ b3,
    const float* __restrict__ gg, const float* __restrict__ off,
    const float* __restrict__ Pm,
    float* __restrict__ outp)
{
  __shared__ __align__(16) unsigned char ldsA2[32*1024];
  __shared__ __align__(16) float ldsB2[128];
  __shared__ __align__(16) unsigned char ldsH[4*4352];

  const int tid  = threadIdx.x;
  const int wid  = tid >> 6;
  const int lane = tid & 63;
  const int p    = lane & 15;
  const int g    = lane >> 4;
  unsigned char* hb = ldsH + wid*4352;
  const long base_pt = (long)blockIdx.x*512 + wid*128;
  const f32x4 z4 = {0.f,0.f,0.f,0.f};
  const h16x8 zh = {(_Float16)0,(_Float16)0,(_Float16)0,(_Float16)0,
                    (_Float16)0,(_Float16)0,(_Float16)0,(_Float16)0};

  f32x4 xst[8];
  #pragma unroll
  for (int s = 0; s < 8; ++s) {
    long pt = base_pt + s*16 + p;
    xst[s][0] = XYZ[pt*3+0];
    xst[s][1] = XYZ[pt*3+1];
    xst[s][2] = XYZ[pt*3+2];
    xst[s][3] = 0.f;
  }

  for (int l = 0; l < 8; ++l) {
    __syncthreads();   // prev layer's A2/b2 reads complete before overwrite

    // ---- cooperative staging: wave wid stages A2 frags wid*8..wid*8+7 (f16) ----
    #pragma unroll
    for (int q = 0; q < 8; ++q) {
      int f  = wid*8 + q;
      int mf = f >> 2, kc = f & 3;
      const float* rw = W2 + l*16384 + (16*mf + p)*128 + 32*kc + 8*g;
      f32x4 u0 = *(const f32x4*)rw;
      f32x4 u1 = *(const f32x4*)(rw + 4);
      i32x4 w;
      w[0] = (int)pkh(u0[0], u0[1]); w[1] = (int)pkh(u0[2], u0[3]);
      w[2] = (int)pkh(u1[0], u1[1]); w[3] = (int)pkh(u1[2], u1[3]);
      *(i32x4*)(ldsA2 + f*1024 + lane*16) = w;
    }
    if (tid < 128) ldsB2[tid] = b2[l*128 + tid];

    // ---- per-wave register fragments: A1 (W1+b1 aug), A3 (0.1*W3) in f16 ----
    h16x8 A1[8];
    #pragma unroll
    for (int mf = 0; mf < 8; ++mf) {
      h16x8 t = zh;
      if (g == 0) {
        int row = 16*mf + p;
        t[0] = (_Float16)W1[l*256 + row*2 + 0];
        t[1] = (_Float16)W1[l*256 + row*2 + 1];
        t[2] = (_Float16)b1[l*128 + row];
      }
      A1[mf] = t;
    }
    h16x8 A3[4];
    #pragma unroll
    for (int kc = 0; kc < 4; ++kc) {
      h16x8 t = zh;
      if (p < 4) {
        const float* rw = W3 + l*512 + p*128 + 8*g + 32*kc;
        f32x4 u0 = *(const f32x4*)(rw);
        f32x4 u1 = *(const f32x4*)(rw + 4);
        i32x4 w;
        w[0] = (int)pkh(0.1f*u0[0], 0.1f*u0[1]); w[1] = (int)pkh(0.1f*u0[2], 0.1f*u0[3]);
        w[2] = (int)pkh(0.1f*u1[0], 0.1f*u1[1]); w[3] = (int)pkh(0.1f*u1[2], 0.1f*u1[3]);
        __builtin_memcpy(&t, &w, 16);
      }
      A3[kc] = t;
    }
    f32x4 b3v = z4;
    if (g == 0) {
      f32x4 t = *(const f32x4*)(b3 + l*4);
      #pragma unroll
      for (int i = 0; i < 4; ++i) b3v[i] = 0.1f*t[i];
    }
    float scl[4];
    #pragma unroll
    for (int j = 0; j < 4; ++j)
      scl[j] = 0.2f * log1pf(expf(0.5f * gg[l*4 + j]));
    float PS[16], PB[4];
    #pragma unroll
    for (int i = 0; i < 4; ++i) {
      float acc = 0.f;
      #pragma unroll
      for (int j = 0; j < 4; ++j) {
        float pv = Pm[l*16 + 4*i + j];
        PS[4*i+j] = pv*scl[j];
        acc = __builtin_fmaf(pv, off[l*4+j], acc);
      }
      PB[i] = acc;
    }

    __syncthreads();   // A2/b2 staged before any wave reads

    #pragma unroll
    for (int s = 0; s < 8; ++s) {
      // ---- G1: h1 = gelu(W1aug @ [x0;x1;1]) ----
      h16x8 bx = zh;
      if (g == 0) {
        bx[0] = (_Float16)xst[s][0];
        bx[1] = (_Float16)xst[s][1];
        bx[2] = (_Float16)1.0f;
      }
      f32x4 c1[8];
      #pragma unroll
      for (int mf = 0; mf < 8; ++mf) c1[mf] = MFMA(A1[mf], bx, z4);

      MEMBAR();
      #pragma unroll
      for (int m = 0; m < 4; ++m) {     // packed-f16 h write (same byte layout)
        i32x4 w;
        unsigned w0,w1,w2,w3;
        gelu4(c1[2*m],   w0, w1);
        gelu4(c1[2*m+1], w2, w3);
        w[0]=(int)w0; w[1]=(int)w1; w[2]=(int)w2; w[3]=(int)w3;
        *(i32x4*)(hb + p*272 + (4*m + g)*16) = w;
      }
      MEMBAR();

      // ---- G2: h2 = gelu(W2 @ h1 + b2); bias C-init from LDS broadcast ----
      f32x4 c2[8];
      #pragma unroll
      for (int mf = 0; mf < 8; ++mf)
        c2[mf] = *(const f32x4*)&ldsB2[16*mf + 4*g];
      #pragma unroll
      for (int kc = 0; kc < 4; ++kc) {
        const unsigned char* ra = hb + p*272 + (4*kc + 2*(g & 1))*16 + (g >> 1)*8;
        s16x4 lo = *(const s16x4*)(ra);
        s16x4 hi = *(const s16x4*)(ra + 16);
        h16x8 bfr;
        __builtin_memcpy(&bfr, &lo, 8);
        __builtin_memcpy(((char*)&bfr)+8, &hi, 8);
        #pragma unroll
        for (int mf = 0; mf < 8; ++mf) {
          h16x8 af = *(const h16x8*)(ldsA2 + (mf*4 + kc)*1024 + lane*16);
          c2[mf] = MFMA(af, bfr, c2[mf]);
        }
      }

      MEMBAR();
      #pragma unroll
      for (int m = 0; m < 4; ++m) {
        i32x4 w;
        unsigned w0,w1,w2,w3;
        gelu4(c2[2*m],   w0, w1);
        gelu4(c2[2*m+1], w2, w3);
        w[0]=(int)w0; w[1]=(int)w1; w[2]=(int)w2; w[3]=(int)w3;
        *(i32x4*)(hb + p*272 + (4*m + g)*16) = w;
      }
      MEMBAR();

      // ---- G3: a = 0.1*(W3 @ h2) + 0.1*b3 (bias as C-init) ----
      f32x4 c3 = b3v;
      #pragma unroll
      for (int kc = 0; kc < 4; ++kc) {
        const unsigned char* ra = hb + p*272 + (4*kc + 2*(g & 1))*16 + (g >> 1)*8;
        s16x4 lo = *(const s16x4*)(ra);
        s16x4 hi = *(const s16x4*)(ra + 16);
        h16x8 bfr;
        __builtin_memcpy(&bfr, &lo, 8);
        __builtin_memcpy(((char*)&bfr)+8, &hi, 8);
        c3 = MFMA(A3[kc], bfr, c3);
      }

      // broadcast a[0..3] (rows 0..3 live on lanes 0..15) to all lanes
      int addr = p << 2;
      float a0 = __int_as_float(__builtin_amdgcn_ds_bpermute(addr, __float_as_int(c3[0])));
      float a1 = __int_as_float(__builtin_amdgcn_ds_bpermute(addr, __float_as_int(c3[1])));
      float a2 = __int_as_float(__builtin_amdgcn_ds_bpermute(addr, __float_as_int(c3[2])));
      float a3 = __int_as_float(__builtin_amdgcn_ds_bpermute(addr, __float_as_int(c3[3])));

      // tail: s=2tanh(a) => exp(s) = exp2(2.8853901 - 5.7707802/(1+exp2(2.8853901*a)))
      float t0 = __builtin_amdgcn_rcpf(1.f + __builtin_amdgcn_exp2f(2.8853901f * a0));
      float t1 = __builtin_amdgcn_rcpf(1.f + __builtin_amdgcn_exp2f(2.8853901f * a1));
      float e0 = __builtin_amdgcn_exp2f(__builtin_fmaf(-5.7707802f, t0, 2.8853901f));
      float e1 = __builtin_amdgcn_exp2f(__builtin_fmaf(-5.7707802f, t1, 2.8853901f));
      float v2 = __builtin_fmaf(xst[s][2], e0, a2);
      float v3 = __builtin_fmaf(xst[s][3], e1, a3);
      f32x4 y;
      #pragma unroll
      for (int i = 0; i < 4; ++i)
        y[i] = __builtin_fmaf(PS[4*i+0], xst[s][0], __builtin_fmaf(PS[4*i+1], xst[s][1],
               __builtin_fmaf(PS[4*i+2], v2, __builtin_fmaf(PS[4*i+3], v3, PB[i]))));
      xst[s] = y;   // replicated across all lanes
    }
  }

  if (g == 0) {
    #pragma unroll
    for (int s = 0; s < 8; ++s) {
      long pt = base_pt + s*16 + p;
      outp[pt*3+0] = xst[s][0];
      outp[pt*3+1] = xst[s][1];
      outp[pt*3+2] = xst[s][2];
    }
  }
}

extern "C" void kernel_launch(void* const* d_in, const int* in_sizes, int n_in,
                              void* d_out, int out_size, void* d_ws, size_t ws_size,
                              hipStream_t stream)
{
  const float* XYZ = (const float*)d_in[0];
  const float* W1  = (const float*)d_in[1];
  const float* b1  = (const float*)d_in[2];
  const float* W2  = (const float*)d_in[3];
  const float* b2  = (const float*)d_in[4];
  const float* W3  = (const float*)d_in[5];
  const float* b3  = (const float*)d_in[6];
  const float* g   = (const float*)d_in[7];
  const float* off = (const float*)d_in[8];
  const float* P   = (const float*)d_in[9];

  int Bn = in_sizes[0] / 3;          // 524288
  int nblocks = Bn / 512;            // 1024 exact
  inn_main<<<nblocks, 256, 0, stream>>>(XYZ, W1, b1, W2, b2, W3, b3, g, off, P,
                                        (float*)d_out);
}

// Round 13
// 411.927 us; speedup vs baseline: 1.5307x; 1.1035x over previous
//
#include <hip/hip_runtime.h>
#include <hip/hip_bf16.h>

// ColorINN R13: s-slot PAIRING. Two point-slots per iteration share one pass
// over the A2 LDS fragments (reads halved) and interleave two independent
// MFMA/GELU streams (2x ILP in the serial chain). h-fragment reads hoisted to
// registers (bfrA/bfrB). Datapath f16 (mfma_f32_16x16x32_f16) + deg-9 poly
// GELU from R12. 256-thr blocks, wave = 128 pts, A2+b2 in LDS.

#define MEMBAR() asm volatile("" ::: "memory")

typedef float    f32x4 __attribute__((ext_vector_type(4)));
typedef short    s16x4 __attribute__((ext_vector_type(4)));
typedef int      i32x4 __attribute__((ext_vector_type(4)));
typedef _Float16 h16x2 __attribute__((ext_vector_type(2)));
typedef _Float16 h16x8 __attribute__((ext_vector_type(8)));

#define MFMA(a,b,c) __builtin_amdgcn_mfma_f32_16x16x32_f16((a),(b),(c),0,0,0)

__device__ __forceinline__ h16x2 pkrtz(float a, float b){
  auto t = __builtin_amdgcn_cvt_pkrtz(a, b);
  h16x2 r; __builtin_memcpy(&r, &t, 4); return r;
}
__device__ __forceinline__ unsigned pkh(float a, float b){
  auto t = __builtin_amdgcn_cvt_pkrtz(a, b);
  unsigned r; __builtin_memcpy(&r, &t, 4); return r;
}

// packed GELU: y = x * (0.5 + xc*D(xc^2)), xc = clamp(x,±3.75)/4, deg-9 odd.
__device__ __forceinline__ h16x2 gelu_pk(h16x2 x){
  const h16x2 Q   = {(_Float16)0.25f,      (_Float16)0.25f};
  const h16x2 CLO = {(_Float16)-0.9375f,   (_Float16)-0.9375f};
  const h16x2 CHI = {(_Float16)0.9375f,    (_Float16)0.9375f};
  const h16x2 D4  = {(_Float16)2.639031f,  (_Float16)2.639031f};
  const h16x2 D3  = {(_Float16)-6.920503f, (_Float16)-6.920503f};
  const h16x2 D2  = {(_Float16)7.180759f,  (_Float16)7.180759f};
  const h16x2 D1  = {(_Float16)-3.960064f, (_Float16)-3.960064f};
  const h16x2 D0  = {(_Float16)1.590628f,  (_Float16)1.590628f};
  const h16x2 H   = {(_Float16)0.5f,       (_Float16)0.5f};
  h16x2 xs = x * Q;
  xs = __builtin_elementwise_max(xs, CLO);
  xs = __builtin_elementwise_min(xs, CHI);
  h16x2 t = xs * xs;
  h16x2 s = t*D4 + D3;
  s = s*t + D2;
  s = s*t + D1;
  s = s*t + D0;
  h16x2 phi = xs*s + H;
  return x * phi;
}

__device__ __forceinline__ void gelu4(const f32x4 c, unsigned& w0, unsigned& w1){
  h16x2 p0 = gelu_pk(pkrtz(c[0], c[1]));
  h16x2 p1 = gelu_pk(pkrtz(c[2], c[3]));
  __builtin_memcpy(&w0, &p0, 4);
  __builtin_memcpy(&w1, &p1, 4);
}

__global__ __launch_bounds__(256, 2) void inn_main(
    const float* __restrict__ XYZ,
    const float* __restrict__ W1, const float* __restrict__ b1,
    const float* __restrict__ W2, const float* __restrict__ b2,
    const float* __restrict__ W3, const float* __restrict__ b3,
    const float* __restrict__ gg, const float* __restrict__ off,
    const float* __restrict__ Pm,
    float* __restrict__ outp)
{
  __shared__ __align__(16) unsigned char ldsA2[32*1024];
  __shared__ __align__(16) float ldsB2[128];
  __shared__ __align__(16) unsigned char ldsH[4*4352];

  const int tid  = threadIdx.x;
  const int wid  = tid >> 6;
  const int lane = tid & 63;
  const int p    = lane & 15;
  const int g    = lane >> 4;
  unsigned char* hb = ldsH + wid*4352;
  const long base_pt = (long)blockIdx.x*512 + wid*128;
  const f32x4 z4 = {0.f,0.f,0.f,0.f};
  const h16x8 zh = {(_Float16)0,(_Float16)0,(_Float16)0,(_Float16)0,
                    (_Float16)0,(_Float16)0,(_Float16)0,(_Float16)0};

  f32x4 xst[8];
  #pragma unroll
  for (int s = 0; s < 8; ++s) {
    long pt = base_pt + s*16 + p;
    xst[s][0] = XYZ[pt*3+0];
    xst[s][1] = XYZ[pt*3+1];
    xst[s][2] = XYZ[pt*3+2];
    xst[s][3] = 0.f;
  }

  for (int l = 0; l < 8; ++l) {
    __syncthreads();   // prev layer's A2/b2 reads complete before overwrite

    // ---- cooperative staging: wave wid stages A2 frags wid*8..wid*8+7 (f16) ----
    #pragma unroll
    for (int q = 0; q < 8; ++q) {
      int f  = wid*8 + q;
      int mf = f >> 2, kc = f & 3;
      const float* rw = W2 + l*16384 + (16*mf + p)*128 + 32*kc + 8*g;
      f32x4 u0 = *(const f32x4*)rw;
      f32x4 u1 = *(const f32x4*)(rw + 4);
      i32x4 w;
      w[0] = (int)pkh(u0[0], u0[1]); w[1] = (int)pkh(u0[2], u0[3]);
      w[2] = (int)pkh(u1[0], u1[1]); w[3] = (int)pkh(u1[2], u1[3]);
      *(i32x4*)(ldsA2 + f*1024 + lane*16) = w;
    }
    if (tid < 128) ldsB2[tid] = b2[l*128 + tid];

    // ---- per-wave register fragments: A1 (W1+b1 aug), A3 (0.1*W3) ----
    h16x8 A1[8];
    #pragma unroll
    for (int mf = 0; mf < 8; ++mf) {
      h16x8 t = zh;
      if (g == 0) {
        int row = 16*mf + p;
        t[0] = (_Float16)W1[l*256 + row*2 + 0];
        t[1] = (_Float16)W1[l*256 + row*2 + 1];
        t[2] = (_Float16)b1[l*128 + row];
      }
      A1[mf] = t;
    }
    h16x8 A3[4];
    #pragma unroll
    for (int kc = 0; kc < 4; ++kc) {
      h16x8 t = zh;
      if (p < 4) {
        const float* rw = W3 + l*512 + p*128 + 8*g + 32*kc;
        f32x4 u0 = *(const f32x4*)(rw);
        f32x4 u1 = *(const f32x4*)(rw + 4);
        i32x4 w;
        w[0] = (int)pkh(0.1f*u0[0], 0.1f*u0[1]); w[1] = (int)pkh(0.1f*u0[2], 0.1f*u0[3]);
        w[2] = (int)pkh(0.1f*u1[0], 0.1f*u1[1]); w[3] = (int)pkh(0.1f*u1[2], 0.1f*u1[3]);
        __builtin_memcpy(&t, &w, 16);
      }
      A3[kc] = t;
    }
    f32x4 b3v = z4;
    if (g == 0) {
      f32x4 t = *(const f32x4*)(b3 + l*4);
      #pragma unroll
      for (int i = 0; i < 4; ++i) b3v[i] = 0.1f*t[i];
    }
    float scl[4];
    #pragma unroll
    for (int j = 0; j < 4; ++j)
      scl[j] = 0.2f * log1pf(expf(0.5f * gg[l*4 + j]));
    float PS[16], PB[4];
    #pragma unroll
    for (int i = 0; i < 4; ++i) {
      float acc = 0.f;
      #pragma unroll
      for (int j = 0; j < 4; ++j) {
        float pv = Pm[l*16 + 4*i + j];
        PS[4*i+j] = pv*scl[j];
        acc = __builtin_fmaf(pv, off[l*4+j], acc);
      }
      PB[i] = acc;
    }

    __syncthreads();   // A2/b2 staged before any wave reads

    #pragma unroll
    for (int sp = 0; sp < 4; ++sp) {
      const int sA = 2*sp, sB = 2*sp+1;

      // ---- G1 for both slots (independent MFMA streams) ----
      h16x8 bxA = zh, bxB = zh;
      if (g == 0) {
        bxA[0] = (_Float16)xst[sA][0]; bxA[1] = (_Float16)xst[sA][1]; bxA[2] = (_Float16)1.0f;
        bxB[0] = (_Float16)xst[sB][0]; bxB[1] = (_Float16)xst[sB][1]; bxB[2] = (_Float16)1.0f;
      }
      f32x4 c1A[8], c1B[8];
      #pragma unroll
      for (int mf = 0; mf < 8; ++mf) c1A[mf] = MFMA(A1[mf], bxA, z4);
      #pragma unroll
      for (int mf = 0; mf < 8; ++mf) c1B[mf] = MFMA(A1[mf], bxB, z4);

      // ---- h1(A) write -> bfrA regs ----
      MEMBAR();
      #pragma unroll
      for (int m = 0; m < 4; ++m) {
        i32x4 w; unsigned w0,w1,w2,w3;
        gelu4(c1A[2*m],   w0, w1);
        gelu4(c1A[2*m+1], w2, w3);
        w[0]=(int)w0; w[1]=(int)w1; w[2]=(int)w2; w[3]=(int)w3;
        *(i32x4*)(hb + p*272 + (4*m + g)*16) = w;
      }
      MEMBAR();
      h16x8 bfrA[4];
      #pragma unroll
      for (int kc = 0; kc < 4; ++kc) {
        const unsigned char* ra = hb + p*272 + (4*kc + 2*(g & 1))*16 + (g >> 1)*8;
        s16x4 lo = *(const s16x4*)(ra);
        s16x4 hi = *(const s16x4*)(ra + 16);
        h16x8 t;
        __builtin_memcpy(&t, &lo, 8);
        __builtin_memcpy(((char*)&t)+8, &hi, 8);
        bfrA[kc] = t;
      }
      MEMBAR();   // bfrA reads complete before h1(B) overwrite (DS in-order)

      // ---- h1(B) write -> bfrB regs ----
      #pragma unroll
      for (int m = 0; m < 4; ++m) {
        i32x4 w; unsigned w0,w1,w2,w3;
        gelu4(c1B[2*m],   w0, w1);
        gelu4(c1B[2*m+1], w2, w3);
        w[0]=(int)w0; w[1]=(int)w1; w[2]=(int)w2; w[3]=(int)w3;
        *(i32x4*)(hb + p*272 + (4*m + g)*16) = w;
      }
      MEMBAR();
      h16x8 bfrB[4];
      #pragma unroll
      for (int kc = 0; kc < 4; ++kc) {
        const unsigned char* ra = hb + p*272 + (4*kc + 2*(g & 1))*16 + (g >> 1)*8;
        s16x4 lo = *(const s16x4*)(ra);
        s16x4 hi = *(const s16x4*)(ra + 16);
        h16x8 t;
        __builtin_memcpy(&t, &lo, 8);
        __builtin_memcpy(((char*)&t)+8, &hi, 8);
        bfrB[kc] = t;
      }
      MEMBAR();

      // ---- G2 paired: one A2 pass feeds both slots ----
      f32x4 c2A[8], c2B[8];
      #pragma unroll
      for (int mf = 0; mf < 8; ++mf) {
        f32x4 bv = *(const f32x4*)&ldsB2[16*mf + 4*g];
        c2A[mf] = bv; c2B[mf] = bv;
      }
      #pragma unroll
      for (int kc = 0; kc < 4; ++kc) {
        #pragma unroll
        for (int mf = 0; mf < 8; ++mf) {
          h16x8 af = *(const h16x8*)(ldsA2 + (mf*4 + kc)*1024 + lane*16);
          c2A[mf] = MFMA(af, bfrA[kc], c2A[mf]);
          c2B[mf] = MFMA(af, bfrB[kc], c2B[mf]);
        }
      }

      // ---- h2(A) write -> G3(A) ----
      MEMBAR();
      #pragma unroll
      for (int m = 0; m < 4; ++m) {
        i32x4 w; unsigned w0,w1,w2,w3;
        gelu4(c2A[2*m],   w0, w1);
        gelu4(c2A[2*m+1], w2, w3);
        w[0]=(int)w0; w[1]=(int)w1; w[2]=(int)w2; w[3]=(int)w3;
        *(i32x4*)(hb + p*272 + (4*m + g)*16) = w;
      }
      MEMBAR();
      f32x4 c3A = b3v;
      #pragma unroll
      for (int kc = 0; kc < 4; ++kc) {
        const unsigned char* ra = hb + p*272 + (4*kc + 2*(g & 1))*16 + (g >> 1)*8;
        s16x4 lo = *(const s16x4*)(ra);
        s16x4 hi = *(const s16x4*)(ra + 16);
        h16x8 bfr;
        __builtin_memcpy(&bfr, &lo, 8);
        __builtin_memcpy(((char*)&bfr)+8, &hi, 8);
        c3A = MFMA(A3[kc], bfr, c3A);
      }
      MEMBAR();   // G3(A) reads before h2(B) overwrite

      // ---- h2(B) write -> G3(B) ----
      #pragma unroll
      for (int m = 0; m < 4; ++m) {
        i32x4 w; unsigned w0,w1,w2,w3;
        gelu4(c2B[2*m],   w0, w1);
        gelu4(c2B[2*m+1], w2, w3);
        w[0]=(int)w0; w[1]=(int)w1; w[2]=(int)w2; w[3]=(int)w3;
        *(i32x4*)(hb + p*272 + (4*m + g)*16) = w;
      }
      MEMBAR();
      f32x4 c3B = b3v;
      #pragma unroll
      for (int kc = 0; kc < 4; ++kc) {
        const unsigned char* ra = hb + p*272 + (4*kc + 2*(g & 1))*16 + (g >> 1)*8;
        s16x4 lo = *(const s16x4*)(ra);
        s16x4 hi = *(const s16x4*)(ra + 16);
        h16x8 bfr;
        __builtin_memcpy(&bfr, &lo, 8);
        __builtin_memcpy(((char*)&bfr)+8, &hi, 8);
        c3B = MFMA(A3[kc], bfr, c3B);
      }
      MEMBAR();

      // ---- tails ----
      {
        int addr = p << 2;
        float a0 = __int_as_float(__builtin_amdgcn_ds_bpermute(addr, __float_as_int(c3A[0])));
        float a1 = __int_as_float(__builtin_amdgcn_ds_bpermute(addr, __float_as_int(c3A[1])));
        float a2 = __int_as_float(__builtin_amdgcn_ds_bpermute(addr, __float_as_int(c3A[2])));
        float a3 = __int_as_float(__builtin_amdgcn_ds_bpermute(addr, __float_as_int(c3A[3])));
        float t0 = __builtin_amdgcn_rcpf(1.f + __builtin_amdgcn_exp2f(2.8853901f * a0));
        float t1 = __builtin_amdgcn_rcpf(1.f + __builtin_amdgcn_exp2f(2.8853901f * a1));
        float e0 = __builtin_amdgcn_exp2f(__builtin_fmaf(-5.7707802f, t0, 2.8853901f));
        float e1 = __builtin_amdgcn_exp2f(__builtin_fmaf(-5.7707802f, t1, 2.8853901f));
        float v2 = __builtin_fmaf(xst[sA][2], e0, a2);
        float v3 = __builtin_fmaf(xst[sA][3], e1, a3);
        f32x4 y;
        #pragma unroll
        for (int i = 0; i < 4; ++i)
          y[i] = __builtin_fmaf(PS[4*i+0], xst[sA][0], __builtin_fmaf(PS[4*i+1], xst[sA][1],
                 __builtin_fmaf(PS[4*i+2], v2, __builtin_fmaf(PS[4*i+3], v3, PB[i]))));
        xst[sA] = y;
      }
      {
        int addr = p << 2;
        float a0 = __int_as_float(__builtin_amdgcn_ds_bpermute(addr, __float_as_int(c3B[0])));
        float a1 = __int_as_float(__builtin_amdgcn_ds_bpermute(addr, __float_as_int(c3B[1])));
        float a2 = __int_as_float(__builtin_amdgcn_ds_bpermute(addr, __float_as_int(c3B[2])));
        float a3 = __int_as_float(__builtin_amdgcn_ds_bpermute(addr, __float_as_int(c3B[3])));
        float t0 = __builtin_amdgcn_rcpf(1.f + __builtin_amdgcn_exp2f(2.8853901f * a0));
        float t1 = __builtin_amdgcn_rcpf(1.f + __builtin_amdgcn_exp2f(2.8853901f * a1));
        float e0 = __builtin_amdgcn_exp2f(__builtin_fmaf(-5.7707802f, t0, 2.8853901f));
        float e1 = __builtin_amdgcn_exp2f(__builtin_fmaf(-5.7707802f, t1, 2.8853901f));
        float v2 = __builtin_fmaf(xst[sB][2], e0, a2);
        float v3 = __builtin_fmaf(xst[sB][3], e1, a3);
        f32x4 y;
        #pragma unroll
        for (int i = 0; i < 4; ++i)
          y[i] = __builtin_fmaf(PS[4*i+0], xst[sB][0], __builtin_fmaf(PS[4*i+1], xst[sB][1],
                 __builtin_fmaf(PS[4*i+2], v2, __builtin_fmaf(PS[4*i+3], v3, PB[i]))));
        xst[sB] = y;
      }
    }
  }

  if (g == 0) {
    #pragma unroll
    for (int s = 0; s < 8; ++s) {
      long pt = base_pt + s*16 + p;
      outp[pt*3+0] = xst[s][0];
      outp[pt*3+1] = xst[s][1];
      outp[pt*3+2] = xst[s][2];
    }
  }
}

extern "C" void kernel_launch(void* const* d_in, const int* in_sizes, int n_in,
                              void* d_out, int out_size, void* d_ws, size_t ws_size,
                              hipStream_t stream)
{
  const float* XYZ = (const float*)d_in[0];
  const float* W1  = (const float*)d_in[1];
  const float* b1  = (const float*)d_in[2];
  const float* W2  = (const float*)d_in[3];
  const float* b2  = (const float*)d_in[4];
  const float* W3  = (const float*)d_in[5];
  const float* b3  = (const float*)d_in[6];
  const float* g   = (const float*)d_in[7];
  const float* off = (const float*)d_in[8];
  const float* P   = (const float*)d_in[9];

  int Bn = in_sizes[0] / 3;          // 524288
  int nblocks = Bn / 512;            // 1024 exact
  inn_main<<<nblocks, 256, 0, stream>>>(XYZ, W1, b1, W2, b2, W3, b3, g, off, P,
                                        (float*)d_out);
}